// Round 1
// baseline (1657.005 us; speedup 1.0000x reference)
//
#include <hip/hip_runtime.h>

#define N_NODES  50000
#define N_EDGES  800000
#define N_GRAPHS 512
#define HID      64
#define NCLS     5

// ---------------- embedding: x0[n][h] = embed[tok[n]][h] ----------------
__global__ void k_embed(const int* __restrict__ tok, const float* __restrict__ embed,
                        float* __restrict__ x0) {
    int gid = blockIdx.x * blockDim.x + threadIdx.x;   // n*16 + quad
    if (gid >= N_NODES * 16) return;
    int n = gid >> 4, c = gid & 15;
    const float4* erow = (const float4*)(embed + (long)tok[n] * HID);
    ((float4*)(x0 + (long)n * HID))[c] = erow[c];
}

// ---------------- in-degree counts (shared by both layers) ----------------
__global__ void k_deg(const int* __restrict__ dst, int* __restrict__ cnt) {
    int e = blockIdx.x * blockDim.x + threadIdx.x;
    if (e < N_EDGES) atomicAdd(&cnt[dst[e]], 1);
}

__global__ void k_gcnt(const int* __restrict__ batch, int* __restrict__ gcnt) {
    int n = blockIdx.x * blockDim.x + threadIdx.x;
    if (n < N_NODES) atomicAdd(&gcnt[batch[n]], 1);
}

// ---------------- edge scatter-add: agg[dst] += x[src] ----------------
// one thread per (edge, float4-quad): 16 threads/edge, 4 atomics each
__global__ void k_scatter(const int* __restrict__ src, const int* __restrict__ dst,
                          const float* __restrict__ x, float* __restrict__ agg) {
    int gid = blockIdx.x * blockDim.x + threadIdx.x;
    if (gid >= N_EDGES * 16) return;
    int e = gid >> 4, c = gid & 15;
    int s = src[e], d = dst[e];
    float4 v = ((const float4*)(x + (long)s * HID))[c];
    float* a = agg + (long)d * HID + c * 4;
    atomicAdd(a + 0, v.x);
    atomicAdd(a + 1, v.y);
    atomicAdd(a + 2, v.z);
    atomicAdd(a + 3, v.w);
}

// ---------------- per-node transform ----------------
// out[n][h] = relu( sum_k (agg[n][k]/deg[n]) * Wl[h][k] + bl[h] + sum_k x[n][k]*Wr[h][k] )
// 64-node x 64-output tile per block, K=128 ([agg/deg | x]), 4x4 register blocking.
// If batch != nullptr: pool epilogue (atomicAdd into gsum) instead of storing.
__global__ __launch_bounds__(256) void k_transform(
    const float* __restrict__ agg, const int* __restrict__ cnt,
    const float* __restrict__ xin,
    const float* __restrict__ Wl, const float* __restrict__ bl,
    const float* __restrict__ Wr,
    float* __restrict__ xout,
    const int* __restrict__ batch, float* __restrict__ gsum)
{
    __shared__ float As[64][128];   // [node][k]; k<64: agg/deg, k>=64: x
    __shared__ float Bs[128][64];   // [k][h]:  k<64: Wl[h][k],  k>=64: Wr[h][k-64]
    const int tid = threadIdx.x;
    const int n0 = blockIdx.x * 64;

    for (int i = tid; i < 128 * 64; i += 256) {
        int k = i >> 6, h = i & 63;
        Bs[k][h] = (k < 64) ? Wl[h * 64 + k] : Wr[h * 64 + (k - 64)];
    }
    for (int i = tid; i < 64 * 32; i += 256) {
        int n = i >> 5, q = i & 31;
        int node = n0 + n;
        float4 v = make_float4(0.f, 0.f, 0.f, 0.f);
        if (node < N_NODES) {
            if (q < 16) {
                v = ((const float4*)(agg + (long)node * HID))[q];
                float inv = 1.0f / (float)max(cnt[node], 1);
                v.x *= inv; v.y *= inv; v.z *= inv; v.w *= inv;
            } else {
                v = ((const float4*)(xin + (long)node * HID))[q - 16];
            }
        }
        int kk = q * 4;
        As[n][kk + 0] = v.x; As[n][kk + 1] = v.y;
        As[n][kk + 2] = v.z; As[n][kk + 3] = v.w;
    }
    __syncthreads();

    const int tx = tid & 15;   // output quad: h = tx*4..tx*4+3
    const int ty = tid >> 4;   // node quad:   n = n0 + ty*4..+3
    float acc[4][4] = {{0.f}};

    for (int k = 0; k < 128; k += 4) {
        float4 a0 = *(const float4*)&As[ty * 4 + 0][k];
        float4 a1 = *(const float4*)&As[ty * 4 + 1][k];
        float4 a2 = *(const float4*)&As[ty * 4 + 2][k];
        float4 a3 = *(const float4*)&As[ty * 4 + 3][k];
        float4 b0 = *(const float4*)&Bs[k + 0][tx * 4];
        float4 b1 = *(const float4*)&Bs[k + 1][tx * 4];
        float4 b2 = *(const float4*)&Bs[k + 2][tx * 4];
        float4 b3 = *(const float4*)&Bs[k + 3][tx * 4];
        float4 ar[4] = {a0, a1, a2, a3};
#pragma unroll
        for (int i = 0; i < 4; ++i) {
            acc[i][0] += ar[i].x * b0.x + ar[i].y * b1.x + ar[i].z * b2.x + ar[i].w * b3.x;
            acc[i][1] += ar[i].x * b0.y + ar[i].y * b1.y + ar[i].z * b2.y + ar[i].w * b3.y;
            acc[i][2] += ar[i].x * b0.z + ar[i].y * b1.z + ar[i].z * b2.z + ar[i].w * b3.z;
            acc[i][3] += ar[i].x * b0.w + ar[i].y * b1.w + ar[i].z * b2.w + ar[i].w * b3.w;
        }
    }

    float bb0 = bl[tx * 4 + 0], bb1 = bl[tx * 4 + 1];
    float bb2 = bl[tx * 4 + 2], bb3 = bl[tx * 4 + 3];
#pragma unroll
    for (int i = 0; i < 4; ++i) {
        int node = n0 + ty * 4 + i;
        if (node >= N_NODES) break;
        float4 o;
        o.x = fmaxf(acc[i][0] + bb0, 0.f);
        o.y = fmaxf(acc[i][1] + bb1, 0.f);
        o.z = fmaxf(acc[i][2] + bb2, 0.f);
        o.w = fmaxf(acc[i][3] + bb3, 0.f);
        if (batch) {
            int g = batch[node];
            float* gp = gsum + (long)g * HID + tx * 4;
            atomicAdd(gp + 0, o.x);
            atomicAdd(gp + 1, o.y);
            atomicAdd(gp + 2, o.z);
            atomicAdd(gp + 3, o.w);
        } else {
            ((float4*)(xout + (long)node * HID))[tx] = o;
        }
    }
}

// ---------------- head: out[g][c] = (gsum[g]/gcnt[g]) . Wlin[c] + blin[c] ----------------
__global__ void k_final(const float* __restrict__ gsum, const int* __restrict__ gcnt,
                        const float* __restrict__ Wlin, const float* __restrict__ blin,
                        float* __restrict__ out) {
    int g = blockIdx.x, h = threadIdx.x;
    float v = gsum[(long)g * HID + h] / (float)max(gcnt[g], 1);
#pragma unroll
    for (int c = 0; c < NCLS; ++c) {
        float p = v * Wlin[c * HID + h];
        for (int o = 32; o > 0; o >>= 1) p += __shfl_down(p, o, 64);
        if (h == 0) out[g * NCLS + c] = p + blin[c];
    }
}

extern "C" void kernel_launch(void* const* d_in, const int* in_sizes, int n_in,
                              void* d_out, int out_size, void* d_ws, size_t ws_size,
                              hipStream_t stream) {
    const int*   tok   = (const int*)d_in[0];
    const int*   eidx  = (const int*)d_in[1];
    const int*   batch = (const int*)d_in[2];
    const float* embed = (const float*)d_in[3];
    const float* W1l   = (const float*)d_in[4];
    const float* b1l   = (const float*)d_in[5];
    const float* W1r   = (const float*)d_in[6];
    const float* W2l   = (const float*)d_in[7];
    const float* b2l   = (const float*)d_in[8];
    const float* W2r   = (const float*)d_in[9];
    const float* Wlin  = (const float*)d_in[10];
    const float* blin  = (const float*)d_in[11];
    float* out = (float*)d_out;

    const int* src = eidx;
    const int* dst = eidx + N_EDGES;

    char* wsp = (char*)d_ws;
    size_t off = 0;
    auto alloc = [&](size_t bytes) -> void* {
        void* p = wsp + off;
        off = (off + bytes + 255) & ~(size_t)255;
        return p;
    };
    float* x0   = (float*)alloc((size_t)N_NODES * HID * 4);
    float* x1   = (float*)alloc((size_t)N_NODES * HID * 4);
    float* agg  = (float*)alloc((size_t)N_NODES * HID * 4);
    int*   cnt  = (int*)  alloc((size_t)N_NODES * 4);
    float* gsum = (float*)alloc((size_t)N_GRAPHS * HID * 4);
    int*   gcnt = (int*)  alloc((size_t)N_GRAPHS * 4);

    hipMemsetAsync(agg,  0, (size_t)N_NODES * HID * 4, stream);
    hipMemsetAsync(cnt,  0, (size_t)N_NODES * 4, stream);
    hipMemsetAsync(gsum, 0, (size_t)N_GRAPHS * HID * 4, stream);
    hipMemsetAsync(gcnt, 0, (size_t)N_GRAPHS * 4, stream);

    k_embed<<<(N_NODES * 16 + 255) / 256, 256, 0, stream>>>(tok, embed, x0);
    k_deg<<<(N_EDGES + 255) / 256, 256, 0, stream>>>(dst, cnt);
    k_gcnt<<<(N_NODES + 255) / 256, 256, 0, stream>>>(batch, gcnt);

    // Layer 1
    k_scatter<<<(N_EDGES * 16 + 255) / 256, 256, 0, stream>>>(src, dst, x0, agg);
    k_transform<<<(N_NODES + 63) / 64, 256, 0, stream>>>(
        agg, cnt, x0, W1l, b1l, W1r, x1, nullptr, nullptr);

    // Layer 2 (pool fused into epilogue)
    hipMemsetAsync(agg, 0, (size_t)N_NODES * HID * 4, stream);
    k_scatter<<<(N_EDGES * 16 + 255) / 256, 256, 0, stream>>>(src, dst, x1, agg);
    k_transform<<<(N_NODES + 63) / 64, 256, 0, stream>>>(
        agg, cnt, x1, W2l, b2l, W2r, nullptr, batch, gsum);

    k_final<<<N_GRAPHS, 64, 0, stream>>>(gsum, gcnt, Wlin, blin, out);
}

// Round 2
// 438.027 us; speedup vs baseline: 3.7829x; 3.7829x over previous
//
#include <hip/hip_runtime.h>

#define N_NODES  50000
#define N_EDGES  800000
#define N_GRAPHS 512
#define HID      64
#define NCLS     5
#define SCAN_B   ((N_NODES + 255) / 256)   // 196

// ---------------- embedding: x0[n][h] = embed[tok[n]][h] ----------------
__global__ void k_embed(const int* __restrict__ tok, const float* __restrict__ embed,
                        float* __restrict__ x0) {
    int gid = blockIdx.x * blockDim.x + threadIdx.x;   // n*16 + quad
    if (gid >= N_NODES * 16) return;
    int n = gid >> 4, c = gid & 15;
    const float4* erow = (const float4*)(embed + (long)tok[n] * HID);
    ((float4*)(x0 + (long)n * HID))[c] = erow[c];
}

// ---------------- degree / graph counts ----------------
__global__ void k_deg(const int* __restrict__ dst, int* __restrict__ cnt) {
    int e = blockIdx.x * blockDim.x + threadIdx.x;
    if (e < N_EDGES) atomicAdd(&cnt[dst[e]], 1);
}

__global__ void k_gcnt(const int* __restrict__ batch, int* __restrict__ gcnt) {
    int n = blockIdx.x * blockDim.x + threadIdx.x;
    if (n < N_NODES) atomicAdd(&gcnt[batch[n]], 1);
}

// ---------------- exclusive scan of cnt -> row_ptr (3 kernels) ----------------
__global__ void k_scan1(const int* __restrict__ cnt, int* __restrict__ rel,
                        int* __restrict__ bsum) {
    __shared__ int sh[256];
    int i = blockIdx.x * 256 + threadIdx.x;
    int v = (i < N_NODES) ? cnt[i] : 0;
    sh[threadIdx.x] = v;
    __syncthreads();
    for (int o = 1; o < 256; o <<= 1) {
        int t = (threadIdx.x >= o) ? sh[threadIdx.x - o] : 0;
        __syncthreads();
        sh[threadIdx.x] += t;
        __syncthreads();
    }
    if (i < N_NODES) rel[i] = sh[threadIdx.x] - v;     // exclusive within block
    if (threadIdx.x == 255) bsum[blockIdx.x] = sh[255];
}

__global__ void k_scan2(int* __restrict__ bsum, int* __restrict__ boff) {
    __shared__ int sh[256];
    int i = threadIdx.x;
    int v = (i < SCAN_B) ? bsum[i] : 0;
    sh[i] = v;
    __syncthreads();
    for (int o = 1; o < 256; o <<= 1) {
        int t = (i >= o) ? sh[i - o] : 0;
        __syncthreads();
        sh[i] += t;
        __syncthreads();
    }
    if (i < SCAN_B) boff[i] = sh[i] - v;               // exclusive
}

__global__ void k_scan3(const int* __restrict__ rel, const int* __restrict__ boff,
                        int* __restrict__ row_ptr) {
    int i = blockIdx.x * 256 + threadIdx.x;
    if (i < N_NODES) row_ptr[i] = rel[i] + boff[blockIdx.x];
}

// ---------------- CSR fill: esrc sorted by dst ----------------
__global__ void k_fill(const int* __restrict__ src, const int* __restrict__ dst,
                       const int* __restrict__ row_ptr, int* __restrict__ cur,
                       int* __restrict__ esrc) {
    int e = blockIdx.x * blockDim.x + threadIdx.x;
    if (e >= N_EDGES) return;
    int d = dst[e];
    int pos = atomicAdd(&cur[d], 1);
    esrc[row_ptr[d] + pos] = src[e];
}

// ---------------- gather aggregation: one wave per dst node ----------------
// agg[n][h] = (1/max(deg,1)) * sum_{e in in(n)} x[esrc[e]][h]
__global__ __launch_bounds__(256) void k_aggregate(
    const int* __restrict__ row_ptr, const int* __restrict__ cnt,
    const int* __restrict__ esrc, const float* __restrict__ x,
    float* __restrict__ agg) {
    int wave = (blockIdx.x * blockDim.x + threadIdx.x) >> 6;
    int lane = threadIdx.x & 63;
    if (wave >= N_NODES) return;
    int n = wave;
    int beg = row_ptr[n];
    int deg = cnt[n];
    int end = beg + deg;
    float acc = 0.f;
    for (int b = beg; b < end; b += 64) {
        int e = b + lane;
        int s = (e < end) ? esrc[e] : 0;
        int m = min(64, end - b);
        for (int j = 0; j < m; ++j) {
            int sj = __shfl(s, j, 64);
            acc += x[(long)sj * HID + lane];
        }
    }
    agg[(long)n * HID + lane] = acc / (float)max(deg, 1);
}

// ---------------- per-node transform ----------------
// out[n][h] = relu( sum_k agg[n][k]*Wl[h][k] + bl[h] + sum_k x[n][k]*Wr[h][k] )
// (agg already mean-scaled). 64x64 tile, K=128, 4x4 register blocking.
__global__ __launch_bounds__(256) void k_transform(
    const float* __restrict__ agg,
    const float* __restrict__ xin,
    const float* __restrict__ Wl, const float* __restrict__ bl,
    const float* __restrict__ Wr,
    float* __restrict__ xout,
    const int* __restrict__ batch, float* __restrict__ gsum)
{
    __shared__ float As[64][128];   // [node][k]; k<64: agg(mean), k>=64: x
    __shared__ float Bs[128][64];   // [k][h]
    const int tid = threadIdx.x;
    const int n0 = blockIdx.x * 64;

    for (int i = tid; i < 128 * 64; i += 256) {
        int k = i >> 6, h = i & 63;
        Bs[k][h] = (k < 64) ? Wl[h * 64 + k] : Wr[h * 64 + (k - 64)];
    }
    for (int i = tid; i < 64 * 32; i += 256) {
        int n = i >> 5, q = i & 31;
        int node = n0 + n;
        float4 v = make_float4(0.f, 0.f, 0.f, 0.f);
        if (node < N_NODES) {
            if (q < 16) v = ((const float4*)(agg + (long)node * HID))[q];
            else        v = ((const float4*)(xin + (long)node * HID))[q - 16];
        }
        int kk = q * 4;
        As[n][kk + 0] = v.x; As[n][kk + 1] = v.y;
        As[n][kk + 2] = v.z; As[n][kk + 3] = v.w;
    }
    __syncthreads();

    const int tx = tid & 15;   // output quad: h = tx*4..tx*4+3
    const int ty = tid >> 4;   // node quad
    float acc[4][4] = {{0.f}};

    for (int k = 0; k < 128; k += 4) {
        float4 a0 = *(const float4*)&As[ty * 4 + 0][k];
        float4 a1 = *(const float4*)&As[ty * 4 + 1][k];
        float4 a2 = *(const float4*)&As[ty * 4 + 2][k];
        float4 a3 = *(const float4*)&As[ty * 4 + 3][k];
        float4 b0 = *(const float4*)&Bs[k + 0][tx * 4];
        float4 b1 = *(const float4*)&Bs[k + 1][tx * 4];
        float4 b2 = *(const float4*)&Bs[k + 2][tx * 4];
        float4 b3 = *(const float4*)&Bs[k + 3][tx * 4];
        float4 ar[4] = {a0, a1, a2, a3};
#pragma unroll
        for (int i = 0; i < 4; ++i) {
            acc[i][0] += ar[i].x * b0.x + ar[i].y * b1.x + ar[i].z * b2.x + ar[i].w * b3.x;
            acc[i][1] += ar[i].x * b0.y + ar[i].y * b1.y + ar[i].z * b2.y + ar[i].w * b3.y;
            acc[i][2] += ar[i].x * b0.z + ar[i].y * b1.z + ar[i].z * b2.z + ar[i].w * b3.z;
            acc[i][3] += ar[i].x * b0.w + ar[i].y * b1.w + ar[i].z * b2.w + ar[i].w * b3.w;
        }
    }

    float bb0 = bl[tx * 4 + 0], bb1 = bl[tx * 4 + 1];
    float bb2 = bl[tx * 4 + 2], bb3 = bl[tx * 4 + 3];
#pragma unroll
    for (int i = 0; i < 4; ++i) {
        int node = n0 + ty * 4 + i;
        if (node >= N_NODES) break;
        float4 o;
        o.x = fmaxf(acc[i][0] + bb0, 0.f);
        o.y = fmaxf(acc[i][1] + bb1, 0.f);
        o.z = fmaxf(acc[i][2] + bb2, 0.f);
        o.w = fmaxf(acc[i][3] + bb3, 0.f);
        if (batch) {
            int g = batch[node];
            float* gp = gsum + (long)g * HID + tx * 4;
            atomicAdd(gp + 0, o.x);
            atomicAdd(gp + 1, o.y);
            atomicAdd(gp + 2, o.z);
            atomicAdd(gp + 3, o.w);
        } else {
            ((float4*)(xout + (long)node * HID))[tx] = o;
        }
    }
}

// ---------------- head ----------------
__global__ void k_final(const float* __restrict__ gsum, const int* __restrict__ gcnt,
                        const float* __restrict__ Wlin, const float* __restrict__ blin,
                        float* __restrict__ out) {
    int g = blockIdx.x, h = threadIdx.x;
    float v = gsum[(long)g * HID + h] / (float)max(gcnt[g], 1);
#pragma unroll
    for (int c = 0; c < NCLS; ++c) {
        float p = v * Wlin[c * HID + h];
        for (int o = 32; o > 0; o >>= 1) p += __shfl_down(p, o, 64);
        if (h == 0) out[g * NCLS + c] = p + blin[c];
    }
}

extern "C" void kernel_launch(void* const* d_in, const int* in_sizes, int n_in,
                              void* d_out, int out_size, void* d_ws, size_t ws_size,
                              hipStream_t stream) {
    const int*   tok   = (const int*)d_in[0];
    const int*   eidx  = (const int*)d_in[1];
    const int*   batch = (const int*)d_in[2];
    const float* embed = (const float*)d_in[3];
    const float* W1l   = (const float*)d_in[4];
    const float* b1l   = (const float*)d_in[5];
    const float* W1r   = (const float*)d_in[6];
    const float* W2l   = (const float*)d_in[7];
    const float* b2l   = (const float*)d_in[8];
    const float* W2r   = (const float*)d_in[9];
    const float* Wlin  = (const float*)d_in[10];
    const float* blin  = (const float*)d_in[11];
    float* out = (float*)d_out;

    const int* src = eidx;
    const int* dst = eidx + N_EDGES;

    char* wsp = (char*)d_ws;
    size_t off = 0;
    auto alloc = [&](size_t bytes) -> void* {
        void* p = wsp + off;
        off = (off + bytes + 255) & ~(size_t)255;
        return p;
    };
    float* x0      = (float*)alloc((size_t)N_NODES * HID * 4);
    float* x1      = (float*)alloc((size_t)N_NODES * HID * 4);
    float* agg     = (float*)alloc((size_t)N_NODES * HID * 4);
    int*   cnt     = (int*)  alloc((size_t)N_NODES * 4);
    int*   rel     = (int*)  alloc((size_t)N_NODES * 4);
    int*   row_ptr = (int*)  alloc((size_t)N_NODES * 4);
    int*   cur     = (int*)  alloc((size_t)N_NODES * 4);
    int*   bsum    = (int*)  alloc((size_t)SCAN_B * 4);
    int*   boff    = (int*)  alloc((size_t)SCAN_B * 4);
    int*   esrc    = (int*)  alloc((size_t)N_EDGES * 4);
    float* gsum    = (float*)alloc((size_t)N_GRAPHS * HID * 4);
    int*   gcnt    = (int*)  alloc((size_t)N_GRAPHS * 4);

    hipMemsetAsync(cnt,  0, (size_t)N_NODES * 4, stream);
    hipMemsetAsync(cur,  0, (size_t)N_NODES * 4, stream);
    hipMemsetAsync(gsum, 0, (size_t)N_GRAPHS * HID * 4, stream);
    hipMemsetAsync(gcnt, 0, (size_t)N_GRAPHS * 4, stream);

    k_embed<<<(N_NODES * 16 + 255) / 256, 256, 0, stream>>>(tok, embed, x0);
    k_deg<<<(N_EDGES + 255) / 256, 256, 0, stream>>>(dst, cnt);
    k_gcnt<<<(N_NODES + 255) / 256, 256, 0, stream>>>(batch, gcnt);

    // CSR build
    k_scan1<<<SCAN_B, 256, 0, stream>>>(cnt, rel, bsum);
    k_scan2<<<1, 256, 0, stream>>>(bsum, boff);
    k_scan3<<<SCAN_B, 256, 0, stream>>>(rel, boff, row_ptr);
    k_fill<<<(N_EDGES + 255) / 256, 256, 0, stream>>>(src, dst, row_ptr, cur, esrc);

    // Layer 1
    k_aggregate<<<(N_NODES * 64 + 255) / 256, 256, 0, stream>>>(row_ptr, cnt, esrc, x0, agg);
    k_transform<<<(N_NODES + 63) / 64, 256, 0, stream>>>(
        agg, x0, W1l, b1l, W1r, x1, nullptr, nullptr);

    // Layer 2 (pool fused into epilogue)
    k_aggregate<<<(N_NODES * 64 + 255) / 256, 256, 0, stream>>>(row_ptr, cnt, esrc, x1, agg);
    k_transform<<<(N_NODES + 63) / 64, 256, 0, stream>>>(
        agg, x1, W2l, b2l, W2r, nullptr, batch, gsum);

    k_final<<<N_GRAPHS, 64, 0, stream>>>(gsum, gcnt, Wlin, blin, out);
}

// Round 3
// 341.227 us; speedup vs baseline: 4.8560x; 1.2837x over previous
//
#include <hip/hip_runtime.h>

#define N_NODES  50000
#define N_EDGES  800000
#define N_GRAPHS 512
#define HID      64
#define NCLS     5
#define SCAN_B   ((N_NODES + 255) / 256)   // 196

typedef __attribute__((ext_vector_type(8))) short bf16x8;
typedef __attribute__((ext_vector_type(4))) float f32x4;

__device__ inline unsigned short f2bf(float f) {
    unsigned int u = __builtin_bit_cast(unsigned int, f);
    unsigned int r = (u + 0x7FFFu + ((u >> 16) & 1u)) >> 16;   // RNE
    return (unsigned short)r;
}

// ---------------- embedding: x0[n][h] = embed[tok[n]][h] ----------------
__global__ void k_embed(const int* __restrict__ tok, const float* __restrict__ embed,
                        float* __restrict__ x0) {
    int gid = blockIdx.x * blockDim.x + threadIdx.x;   // n*16 + quad
    if (gid >= N_NODES * 16) return;
    int n = gid >> 4, c = gid & 15;
    const float4* erow = (const float4*)(embed + (long)tok[n] * HID);
    ((float4*)(x0 + (long)n * HID))[c] = erow[c];
}

// ---------------- degree / graph counts ----------------
__global__ void k_deg(const int* __restrict__ dst, int* __restrict__ cnt) {
    int e = blockIdx.x * blockDim.x + threadIdx.x;
    if (e < N_EDGES) atomicAdd(&cnt[dst[e]], 1);
}

__global__ void k_gcnt(const int* __restrict__ batch, int* __restrict__ gcnt) {
    int n = blockIdx.x * blockDim.x + threadIdx.x;
    if (n < N_NODES) atomicAdd(&gcnt[batch[n]], 1);
}

// ---------------- exclusive scan of cnt -> row_ptr ----------------
__global__ void k_scan1(const int* __restrict__ cnt, int* __restrict__ rel,
                        int* __restrict__ bsum) {
    __shared__ int sh[256];
    int i = blockIdx.x * 256 + threadIdx.x;
    int v = (i < N_NODES) ? cnt[i] : 0;
    sh[threadIdx.x] = v;
    __syncthreads();
    for (int o = 1; o < 256; o <<= 1) {
        int t = (threadIdx.x >= o) ? sh[threadIdx.x - o] : 0;
        __syncthreads();
        sh[threadIdx.x] += t;
        __syncthreads();
    }
    if (i < N_NODES) rel[i] = sh[threadIdx.x] - v;
    if (threadIdx.x == 255) bsum[blockIdx.x] = sh[255];
}

__global__ void k_scan2(int* __restrict__ bsum, int* __restrict__ boff) {
    __shared__ int sh[256];
    int i = threadIdx.x;
    int v = (i < SCAN_B) ? bsum[i] : 0;
    sh[i] = v;
    __syncthreads();
    for (int o = 1; o < 256; o <<= 1) {
        int t = (i >= o) ? sh[i - o] : 0;
        __syncthreads();
        sh[i] += t;
        __syncthreads();
    }
    if (i < SCAN_B) boff[i] = sh[i] - v;
}

__global__ void k_scan3(const int* __restrict__ rel, const int* __restrict__ boff,
                        int* __restrict__ row_ptr) {
    int i = blockIdx.x * 256 + threadIdx.x;
    if (i < N_NODES) row_ptr[i] = rel[i] + boff[blockIdx.x];
}

// ---------------- CSR fill ----------------
__global__ void k_fill(const int* __restrict__ src, const int* __restrict__ dst,
                       const int* __restrict__ row_ptr, int* __restrict__ cur,
                       int* __restrict__ esrc) {
    int e = blockIdx.x * blockDim.x + threadIdx.x;
    if (e >= N_EDGES) return;
    int d = dst[e];
    int pos = atomicAdd(&cur[d], 1);
    esrc[row_ptr[d] + pos] = src[e];
}

// ---------------- gather aggregation: one wave per dst node ----------------
__global__ __launch_bounds__(256) void k_aggregate(
    const int* __restrict__ row_ptr, const int* __restrict__ cnt,
    const int* __restrict__ esrc, const float* __restrict__ x,
    float* __restrict__ agg) {
    int wave = (blockIdx.x * blockDim.x + threadIdx.x) >> 6;
    int lane = threadIdx.x & 63;
    if (wave >= N_NODES) return;
    int n = wave;
    int beg = row_ptr[n];
    int deg = cnt[n];
    int end = beg + deg;
    float a0 = 0.f, a1 = 0.f, a2 = 0.f, a3 = 0.f;
    for (int b = beg; b < end; b += 64) {
        int e = b + lane;
        int s = (e < end) ? esrc[e] : 0;
        int m = min(64, end - b);
        int j = 0;
        for (; j + 4 <= m; j += 4) {
            int s0 = __shfl(s, j + 0, 64);
            int s1 = __shfl(s, j + 1, 64);
            int s2 = __shfl(s, j + 2, 64);
            int s3 = __shfl(s, j + 3, 64);
            a0 += x[(long)s0 * HID + lane];
            a1 += x[(long)s1 * HID + lane];
            a2 += x[(long)s2 * HID + lane];
            a3 += x[(long)s3 * HID + lane];
        }
        for (; j < m; ++j) {
            int sj = __shfl(s, j, 64);
            a0 += x[(long)sj * HID + lane];
        }
    }
    float acc = (a0 + a1) + (a2 + a3);
    agg[(long)n * HID + lane] = acc / (float)max(deg, 1);
}

// ---------------- per-node transform via bf16 MFMA ----------------
// out[n][h] = relu( [agg(mean) | x] @ [Wl | Wr]^T + bl )  -- M=64/block, N=64, K=128
// A staged bf16 in LDS [64][136]; B = W rows (already B^T layout) bf16 [64][136].
// 4 waves: wave w -> node strip [w*16, w*16+16), all 64 h via 4 htiles x 4 ksteps.
#define ASTRIDE 136
__global__ __launch_bounds__(256) void k_transform(
    const float* __restrict__ agg,
    const float* __restrict__ xin,
    const float* __restrict__ Wl, const float* __restrict__ bl,
    const float* __restrict__ Wr,
    float* __restrict__ xout,
    const int* __restrict__ batch, float* __restrict__ gsum)
{
    __shared__ unsigned short As[64 * ASTRIDE];
    __shared__ unsigned short Bs[64 * ASTRIDE];
    const int tid = threadIdx.x;
    const int n0 = blockIdx.x * 64;

    // stage A: 64 nodes x 32 float4-chunks (k<64: agg, k>=64: xin)
    for (int it = tid; it < 64 * 32; it += 256) {
        int nl = it >> 5, c = it & 31;
        int node = n0 + nl;
        float4 v = make_float4(0.f, 0.f, 0.f, 0.f);
        if (node < N_NODES) {
            if (c < 16) v = ((const float4*)(agg + (long)node * HID))[c];
            else        v = ((const float4*)(xin + (long)node * HID))[c - 16];
        }
        unsigned short* p = As + nl * ASTRIDE + c * 4;
        p[0] = f2bf(v.x); p[1] = f2bf(v.y); p[2] = f2bf(v.z); p[3] = f2bf(v.w);
    }
    // stage B: Bs[h][k] = Wl[h][k] (k<64) / Wr[h][k-64]
    for (int it = tid; it < 64 * 32; it += 256) {
        int h = it >> 5, c = it & 31;
        float4 v;
        if (c < 16) v = ((const float4*)(Wl + (long)h * HID))[c];
        else        v = ((const float4*)(Wr + (long)h * HID))[c - 16];
        unsigned short* p = Bs + h * ASTRIDE + c * 4;
        p[0] = f2bf(v.x); p[1] = f2bf(v.y); p[2] = f2bf(v.z); p[3] = f2bf(v.w);
    }
    __syncthreads();

    const int lane = tid & 63;
    const int w    = tid >> 6;       // wave id -> node strip
    const int m    = lane & 15;
    const int quad = lane >> 4;

    // A fragments: a[kst] = A[w*16+m][kst*32 + quad*8 .. +8)
    bf16x8 afr[4];
#pragma unroll
    for (int kst = 0; kst < 4; ++kst)
        afr[kst] = *(const bf16x8*)(As + (w * 16 + m) * ASTRIDE + kst * 32 + quad * 8);

    f32x4 acc[4];
#pragma unroll
    for (int t = 0; t < 4; ++t) {
        acc[t] = (f32x4){0.f, 0.f, 0.f, 0.f};
#pragma unroll
        for (int kst = 0; kst < 4; ++kst) {
            bf16x8 bfr = *(const bf16x8*)(Bs + (t * 16 + m) * ASTRIDE + kst * 32 + quad * 8);
            acc[t] = __builtin_amdgcn_mfma_f32_16x16x32_bf16(afr[kst], bfr, acc[t], 0, 0, 0);
        }
    }

    // epilogue: C row = quad*4+r (node in strip), col = m (within htile)
#pragma unroll
    for (int t = 0; t < 4; ++t) {
        int h = t * 16 + m;
        float bb = bl[h];
#pragma unroll
        for (int r = 0; r < 4; ++r) {
            int node = n0 + w * 16 + quad * 4 + r;
            if (node >= N_NODES) continue;
            float val = fmaxf(acc[t][r] + bb, 0.f);
            if (batch) {
                atomicAdd(&gsum[(long)batch[node] * HID + h], val);
            } else {
                xout[(long)node * HID + h] = val;
            }
        }
    }
}

// ---------------- head ----------------
__global__ void k_final(const float* __restrict__ gsum, const int* __restrict__ gcnt,
                        const float* __restrict__ Wlin, const float* __restrict__ blin,
                        float* __restrict__ out) {
    int g = blockIdx.x, h = threadIdx.x;
    float v = gsum[(long)g * HID + h] / (float)max(gcnt[g], 1);
#pragma unroll
    for (int c = 0; c < NCLS; ++c) {
        float p = v * Wlin[c * HID + h];
        for (int o = 32; o > 0; o >>= 1) p += __shfl_down(p, o, 64);
        if (h == 0) out[g * NCLS + c] = p + blin[c];
    }
}

extern "C" void kernel_launch(void* const* d_in, const int* in_sizes, int n_in,
                              void* d_out, int out_size, void* d_ws, size_t ws_size,
                              hipStream_t stream) {
    const int*   tok   = (const int*)d_in[0];
    const int*   eidx  = (const int*)d_in[1];
    const int*   batch = (const int*)d_in[2];
    const float* embed = (const float*)d_in[3];
    const float* W1l   = (const float*)d_in[4];
    const float* b1l   = (const float*)d_in[5];
    const float* W1r   = (const float*)d_in[6];
    const float* W2l   = (const float*)d_in[7];
    const float* b2l   = (const float*)d_in[8];
    const float* W2r   = (const float*)d_in[9];
    const float* Wlin  = (const float*)d_in[10];
    const float* blin  = (const float*)d_in[11];
    float* out = (float*)d_out;

    const int* src = eidx;
    const int* dst = eidx + N_EDGES;

    char* wsp = (char*)d_ws;
    size_t off = 0;
    auto alloc = [&](size_t bytes) -> void* {
        void* p = wsp + off;
        off = (off + bytes + 255) & ~(size_t)255;
        return p;
    };
    float* x0      = (float*)alloc((size_t)N_NODES * HID * 4);
    float* x1      = (float*)alloc((size_t)N_NODES * HID * 4);
    float* agg     = (float*)alloc((size_t)N_NODES * HID * 4);
    int*   cnt     = (int*)  alloc((size_t)N_NODES * 4);
    int*   rel     = (int*)  alloc((size_t)N_NODES * 4);
    int*   row_ptr = (int*)  alloc((size_t)N_NODES * 4);
    int*   cur     = (int*)  alloc((size_t)N_NODES * 4);
    int*   bsum    = (int*)  alloc((size_t)SCAN_B * 4);
    int*   boff    = (int*)  alloc((size_t)SCAN_B * 4);
    int*   esrc    = (int*)  alloc((size_t)N_EDGES * 4);
    float* gsum    = (float*)alloc((size_t)N_GRAPHS * HID * 4);
    int*   gcnt    = (int*)  alloc((size_t)N_GRAPHS * 4);

    hipMemsetAsync(cnt,  0, (size_t)N_NODES * 4, stream);
    hipMemsetAsync(cur,  0, (size_t)N_NODES * 4, stream);
    hipMemsetAsync(gsum, 0, (size_t)N_GRAPHS * HID * 4, stream);
    hipMemsetAsync(gcnt, 0, (size_t)N_GRAPHS * 4, stream);

    k_embed<<<(N_NODES * 16 + 255) / 256, 256, 0, stream>>>(tok, embed, x0);
    k_deg<<<(N_EDGES + 255) / 256, 256, 0, stream>>>(dst, cnt);
    k_gcnt<<<(N_NODES + 255) / 256, 256, 0, stream>>>(batch, gcnt);

    // CSR build
    k_scan1<<<SCAN_B, 256, 0, stream>>>(cnt, rel, bsum);
    k_scan2<<<1, 256, 0, stream>>>(bsum, boff);
    k_scan3<<<SCAN_B, 256, 0, stream>>>(rel, boff, row_ptr);
    k_fill<<<(N_EDGES + 255) / 256, 256, 0, stream>>>(src, dst, row_ptr, cur, esrc);

    // Layer 1
    k_aggregate<<<(N_NODES * 64 + 255) / 256, 256, 0, stream>>>(row_ptr, cnt, esrc, x0, agg);
    k_transform<<<(N_NODES + 63) / 64, 256, 0, stream>>>(
        agg, x0, W1l, b1l, W1r, x1, nullptr, nullptr);

    // Layer 2 (pool fused into epilogue)
    k_aggregate<<<(N_NODES * 64 + 255) / 256, 256, 0, stream>>>(row_ptr, cnt, esrc, x1, agg);
    k_transform<<<(N_NODES + 63) / 64, 256, 0, stream>>>(
        agg, x1, W2l, b2l, W2r, nullptr, batch, gsum);

    k_final<<<N_GRAPHS, 64, 0, stream>>>(gsum, gcnt, Wlin, blin, out);
}